// Round 7
// baseline (1172.225 us; speedup 1.0000x reference)
//
#include <hip/hip_runtime.h>
#include <cstddef>
#include <cstdint>

typedef unsigned short u16;
typedef short bf16x8 __attribute__((ext_vector_type(8)));
typedef float f32x4 __attribute__((ext_vector_type(4)));

// Problem constants (B=16, S=1024, D=768, DC=64, K=8192)
#define NROW   16384
#define DMODEL 768
#define DCODE  64
#define KCODES 8192

// d_out layout (float element offsets): [out 16384*768][loss 1][codex 16384*8192]
#define OUT_LOSS  12582912
#define OUT_CODEX 12582913
// 16B-aligned scratch carved out of the codex region. NOTE: everything here
// (incl. P) is clobbered by onehot_k — all readers MUST complete first
// (stream order). R6 fused gather into onehot and raced on P. Never fuse a
// reader of this region with the one-hot writer.
#define S0        12582916
#define H_OFF     (S0)                        // 12582912 f
#define P_OFF     (H_OFF + 12582912)          // 6291456 f
#define ZN_OFF    (P_OFF + 6291456)           // 1048576 f
#define Q_OFF     (ZN_OFF + 1048576)          // 524288 f
#define ZH_OFF    (Q_OFF + 524288)            // u16 planes of Z: each 6291456 f
#define ZM_OFF    (ZH_OFF + 6291456)
#define ZL_OFF    (ZM_OFF + 6291456)
#define W1H_OFF   (ZL_OFF + 6291456)          // W1^T planes: each 294912 f
#define W1M_OFF   (W1H_OFF + 294912)
#define W1L_OFF   (W1M_OFF + 294912)
#define NH_OFF    (W1L_OFF + 294912)          // Zn planes (hi, mid): each 524288 f
#define NM_OFF    (NH_OFF + 524288)
#define EH_OFF    (NM_OFF + 524288)           // emb planes (hi, mid): each 262144 f
#define EM_OFF    (EH_OFF + 262144)

__device__ __forceinline__ u16 f2bf(float x) {
    unsigned u = __float_as_uint(x);
    u += 0x7fffu + ((u >> 16) & 1u);          // RTNE
    return (u16)(u >> 16);
}
__device__ __forceinline__ float bf2f(u16 h) {
    return __uint_as_float(((unsigned)h) << 16);
}

// async global->LDS, 16 B per lane. LDS dest is wave-uniform base + lane*16
// (m104/m108): callers must pass lds = base + lane*16 exactly.
typedef __attribute__((address_space(1))) const unsigned int gas_u32;
typedef __attribute__((address_space(3))) unsigned int las_u32;
__device__ __forceinline__ void gll16(const u16* g, u16* l) {
    __builtin_amdgcn_global_load_lds((gas_u32*)g, (las_u32*)l, 16, 0, 0);
}

// ---------------------------------------------------------------------------
// Fused prep: blocks [0,6144) split Z into 3 bf16 planes; [6144,6720) split+
// transpose W1 into 3 planes; [6720,8768) emb -> hi/mid planes + Q=LN(emb).
// Block 6144 thread 0 also zeroes the loss slot (replaces a memset launch).
// ---------------------------------------------------------------------------
__global__ __launch_bounds__(256) void prep_k(const float* __restrict__ Z,
                                              const float* __restrict__ W1,
                                              const float* __restrict__ emb,
                                              const float* __restrict__ gamma,
                                              const float* __restrict__ beta,
                                              u16* __restrict__ Ph,
                                              u16* __restrict__ Pm,
                                              u16* __restrict__ Pl,
                                              u16* __restrict__ Th,
                                              u16* __restrict__ Tm,
                                              u16* __restrict__ Tl,
                                              u16* __restrict__ Eh,
                                              u16* __restrict__ Em,
                                              float* __restrict__ Q,
                                              float* __restrict__ lossp) {
    __shared__ float tile[32][33];
    const int b = blockIdx.x, t = threadIdx.x;
    if (b < 6144) {
        // ---- split Z, 8 elems/thread ----
        const size_t g = (size_t)b * 256 + t;
        const float4* zp = reinterpret_cast<const float4*>(Z) + g * 2;
        float4 a = zp[0], bb = zp[1];
        float xs[8] = {a.x, a.y, a.z, a.w, bb.x, bb.y, bb.z, bb.w};
        union { u16 u[8]; uint4 v; } ph, pm, pl;
#pragma unroll
        for (int k = 0; k < 8; ++k) {
            float x = xs[k];
            u16 h = f2bf(x); float r = x - bf2f(h);
            u16 m = f2bf(r); float r2 = r - bf2f(m);
            pl.u[k] = f2bf(r2); ph.u[k] = h; pm.u[k] = m;
        }
        *reinterpret_cast<uint4*>(Ph + g * 8) = ph.v;
        *reinterpret_cast<uint4*>(Pm + g * 8) = pm.v;
        *reinterpret_cast<uint4*>(Pl + g * 8) = pl.v;
    } else if (b < 6720) {
        // ---- split + transpose W1 (32x32 tile) ----
        if (b == 6144 && t == 0) *lossp = 0.0f;
        const int bb = b - 6144;
        const int n0 = (bb % 24) * 32, k0 = (bb / 24) * 32;
        const int tc = t & 31, tr = t >> 5;
#pragma unroll
        for (int rr = 0; rr < 4; ++rr) {
            int r = tr * 4 + rr;
            tile[r][tc] = W1[(size_t)(k0 + r) * 768 + n0 + tc];
        }
        __syncthreads();
#pragma unroll
        for (int rr = 0; rr < 4; ++rr) {
            int n = n0 + tr * 4 + rr;
            int k = k0 + tc;
            float x = tile[tc][tr * 4 + rr];
            u16 h = f2bf(x); float r = x - bf2f(h);
            u16 m = f2bf(r); u16 l = f2bf(r - bf2f(m));
            Th[(size_t)n * 768 + k] = h;
            Tm[(size_t)n * 768 + k] = m;
            Tl[(size_t)n * 768 + k] = l;
        }
    } else {
        // ---- emb hi/mid planes + Q = LN(emb)*gamma+beta, one wave/row ----
        const int lane = t & 63;
        const int n = (b - 6720) * 4 + (t >> 6);
        float x = emb[(size_t)n * 64 + lane];
        u16 h = f2bf(x); float r = x - bf2f(h);
        Eh[(size_t)n * 64 + lane] = h;
        Em[(size_t)n * 64 + lane] = f2bf(r);
        float mu = x;
#pragma unroll
        for (int off = 32; off > 0; off >>= 1) mu += __shfl_xor(mu, off, 64);
        mu *= (1.0f / 64.0f);
        float d = x - mu;
        float var = d * d;
#pragma unroll
        for (int off = 32; off > 0; off >>= 1) var += __shfl_xor(var, off, 64);
        var *= (1.0f / 64.0f);
        Q[(size_t)n * 64 + lane] = d * rsqrtf(var + 1e-5f) * gamma[lane] + beta[lane];
    }
}

// ---------------------------------------------------------------------------
// GEMM1 via 6-product bf16x3 MFMA: H = tanh(Z @ W1 + b1).
// M=16384, N=768, K=768. BM=128, BN=128, BK=32. LDS 48 KiB, 3 blocks/CU.
// global_load_lds(16B) staging, XOR chunk swizzle on the global side.
// ---------------------------------------------------------------------------
#define APL 4096   // u16 per 128x32 plane tile
__global__ __launch_bounds__(256, 3) void gemm1_mfma(
        const u16* __restrict__ Ah0, const u16* __restrict__ Am0, const u16* __restrict__ Al0,
        const u16* __restrict__ Bh0, const u16* __restrict__ Bm0, const u16* __restrict__ Bl0,
        const float* __restrict__ bias, float* __restrict__ H) {
    __shared__ u16 lds[6 * APL];          // A planes 0..2, B planes 3..5

    const int b = blockIdx.x;
    const int xcd = b & 7, ii = b >> 3;
    const int row0 = (xcd * 16 + (ii & 15)) * 128;
    const int col0 = (ii >> 4) * 128;

    const int t = threadIdx.x;
    const int w = t >> 6, lane = t & 63, lm = lane & 15, q = lane >> 4;
    const int wr = (w >> 1) * 64, wc = (w & 1) * 64;

    const u16* Ap[3] = {Ah0, Am0, Al0};
    const u16* Bp[3] = {Bh0, Bm0, Bl0};

    const int sr  = lane >> 2;        // row within 16-row group
    const int scc = lane & 3;         // LDS chunk slot

    f32x4 acc[4][4];
#pragma unroll
    for (int i = 0; i < 4; ++i)
#pragma unroll
        for (int j = 0; j < 4; ++j) acc[i][j] = (f32x4){0.f, 0.f, 0.f, 0.f};

    for (int k0 = 0; k0 < 768; k0 += 32) {
        __syncthreads();
#pragma unroll
        for (int p = 0; p < 3; ++p) {
#pragma unroll
            for (int rr = 0; rr < 2; ++rr) {
                int g = rr * 4 + w;               // 16-row group 0..7
                int r = g * 16 + sr;              // local row 0..127
                int cg = scc ^ ((r >> 1) & 3);    // swizzled source chunk
                gll16(Ap[p] + (size_t)(row0 + r) * 768 + k0 + cg * 8,
                      &lds[p * APL + g * 512 + lane * 8]);
                gll16(Bp[p] + (size_t)(col0 + r) * 768 + k0 + cg * 8,
                      &lds[(3 + p) * APL + g * 512 + lane * 8]);
            }
        }
        __syncthreads();

        bf16x8 fah[4], fam[4], fal[4];
#pragma unroll
        for (int i = 0; i < 4; ++i) {
            int r = wr + i * 16 + lm;
            int off = r * 32 + ((q ^ ((r >> 1) & 3)) * 8);
            fah[i] = *reinterpret_cast<const bf16x8*>(&lds[0 * APL + off]);
            fam[i] = *reinterpret_cast<const bf16x8*>(&lds[1 * APL + off]);
            fal[i] = *reinterpret_cast<const bf16x8*>(&lds[2 * APL + off]);
        }
#pragma unroll
        for (int j = 0; j < 4; ++j) {
            int rb = wc + j * 16 + lm;
            int offb = rb * 32 + ((q ^ ((rb >> 1) & 3)) * 8);
            bf16x8 fbh = *reinterpret_cast<const bf16x8*>(&lds[3 * APL + offb]);
            bf16x8 fbm = *reinterpret_cast<const bf16x8*>(&lds[4 * APL + offb]);
            bf16x8 fbl = *reinterpret_cast<const bf16x8*>(&lds[5 * APL + offb]);
#pragma unroll
            for (int i = 0; i < 4; ++i) {
                f32x4 c = acc[i][j];
                c = __builtin_amdgcn_mfma_f32_16x16x32_bf16(fah[i], fbl, c, 0, 0, 0);
                c = __builtin_amdgcn_mfma_f32_16x16x32_bf16(fal[i], fbh, c, 0, 0, 0);
                c = __builtin_amdgcn_mfma_f32_16x16x32_bf16(fam[i], fbm, c, 0, 0, 0);
                c = __builtin_amdgcn_mfma_f32_16x16x32_bf16(fah[i], fbm, c, 0, 0, 0);
                c = __builtin_amdgcn_mfma_f32_16x16x32_bf16(fam[i], fbh, c, 0, 0, 0);
                c = __builtin_amdgcn_mfma_f32_16x16x32_bf16(fah[i], fbh, c, 0, 0, 0);
                acc[i][j] = c;
            }
        }
    }
    // epilogue: +bias, tanh, store
#pragma unroll
    for (int i = 0; i < 4; ++i)
#pragma unroll
        for (int j = 0; j < 4; ++j) {
            int col = col0 + wc + j * 16 + lm;
            float bv = bias[col];
#pragma unroll
            for (int r = 0; r < 4; ++r) {
                int row = row0 + wr + i * 16 + q * 4 + r;
                H[(size_t)row * 768 + col] = tanhf(acc[i][j][r] + bv);
            }
        }
}

// ---------------------------------------------------------------------------
// GEMM2 fused with l2norm: Zn = l2norm(H @ W2 + b2) + hi/mid bf16 planes.
// M=16384, N=64(full), K=768. fp32 vector. BM=32 -> 512 blocks (2/CU).
// ---------------------------------------------------------------------------
__global__ __launch_bounds__(256) void gemm2_l2(const float* __restrict__ A,
                                                const float* __restrict__ B,
                                                const float* __restrict__ bias,
                                                float* __restrict__ Zn,
                                                u16* __restrict__ Nh,
                                                u16* __restrict__ Nm) {
    __shared__ float As[16][32];
    __shared__ float Bs[16][64];
    const int t    = threadIdx.x;
    const int row0 = blockIdx.x * 32;
    const int tx = t & 15, ty = t >> 4;
    const int ar = t >> 2, ac = (t & 3) << 2;   // t<128 stages A
    const int br = t >> 4, bc = (t & 15) << 2;

    const float* Ap = A + (size_t)(row0 + ar) * 768 + ac;
    const float* Bp = B + (size_t)br * 64 + bc;

    float acc[2][4];
#pragma unroll
    for (int i = 0; i < 2; ++i)
#pragma unroll
        for (int j = 0; j < 4; ++j) acc[i][j] = 0.0f;

    for (int k0 = 0; k0 < 768; k0 += 16) {
        float4 a0;
        if (t < 128) a0 = *reinterpret_cast<const float4*>(Ap + k0);
        float4 b0 = *reinterpret_cast<const float4*>(Bp + (size_t)k0 * 64);
        __syncthreads();
        if (t < 128) {
            As[ac + 0][ar] = a0.x; As[ac + 1][ar] = a0.y;
            As[ac + 2][ar] = a0.z; As[ac + 3][ar] = a0.w;
        }
        *reinterpret_cast<float4*>(&Bs[br][bc]) = b0;
        __syncthreads();
#pragma unroll
        for (int k = 0; k < 16; ++k) {
            float av0 = As[k][ty * 2 + 0];
            float av1 = As[k][ty * 2 + 1];
            float4 xb = *reinterpret_cast<const float4*>(&Bs[k][tx << 2]);
            float bv[4] = {xb.x, xb.y, xb.z, xb.w};
#pragma unroll
            for (int j = 0; j < 4; ++j) {
                acc[0][j] = fmaf(av0, bv[j], acc[0][j]);
                acc[1][j] = fmaf(av1, bv[j], acc[1][j]);
            }
        }
    }
    const int c = tx << 2;
    const float4 bv4 = *reinterpret_cast<const float4*>(bias + c);
#pragma unroll
    for (int i = 0; i < 2; ++i) {
        float v0 = acc[i][0] + bv4.x;
        float v1 = acc[i][1] + bv4.y;
        float v2 = acc[i][2] + bv4.z;
        float v3 = acc[i][3] + bv4.w;
        float ss = v0 * v0 + v1 * v1 + v2 * v2 + v3 * v3;
#pragma unroll
        for (int msk = 1; msk <= 8; msk <<= 1) ss += __shfl_xor(ss, msk, 64);
        float sc = 1.0f / fmaxf(sqrtf(ss), 1e-12f);
        v0 *= sc; v1 *= sc; v2 *= sc; v3 *= sc;
        int r = row0 + ty * 2 + i;
        float4 z = {v0, v1, v2, v3};
        *reinterpret_cast<float4*>(Zn + (size_t)r * 64 + c) = z;
        float vs[4] = {v0, v1, v2, v3};
        u16 hu[4], mu_[4];
#pragma unroll
        for (int j = 0; j < 4; ++j) {
            u16 h = f2bf(vs[j]);
            hu[j] = h; mu_[j] = f2bf(vs[j] - bf2f(h));
        }
        *reinterpret_cast<ushort4*>(Nh + (size_t)r * 64 + c) =
            make_ushort4(hu[0], hu[1], hu[2], hu[3]);
        *reinterpret_cast<ushort4*>(Nm + (size_t)r * 64 + c) =
            make_ushort4(mu_[0], mu_[1], mu_[2], mu_[3]);
    }
}

// ---------------------------------------------------------------------------
// Generic 128x128x16 fp32 tiled GEMM (used for P = Q @ Wp + bp, K=64).
// ---------------------------------------------------------------------------
__global__ __launch_bounds__(256) void gemm128(const float* __restrict__ A,
                                               const float* __restrict__ B,
                                               const float* __restrict__ bias,
                                               float* __restrict__ C,
                                               int M, int N, int K) {
    __shared__ float As[16][128];
    __shared__ float Bs[16][128];
    const int t    = threadIdx.x;
    const int row0 = blockIdx.y * 128;
    const int col0 = blockIdx.x * 128;
    const int tx = t & 15, ty = t >> 4;
    const int ar = t >> 2, ac = (t & 3) << 2;
    const int br = t >> 5, bc = (t & 31) << 2;

    const float* Ap0 = A + (size_t)(row0 + ar) * K + ac;
    const float* Ap1 = Ap0 + (size_t)64 * K;
    const float* Bp0 = B + (size_t)br * N + col0 + bc;
    const float* Bp1 = Bp0 + (size_t)8 * N;

    float acc[8][8];
#pragma unroll
    for (int i = 0; i < 8; ++i)
#pragma unroll
        for (int j = 0; j < 8; ++j) acc[i][j] = 0.0f;

    for (int k0 = 0; k0 < K; k0 += 16) {
        float4 a0 = *reinterpret_cast<const float4*>(Ap0 + k0);
        float4 a1 = *reinterpret_cast<const float4*>(Ap1 + k0);
        float4 b0 = *reinterpret_cast<const float4*>(Bp0 + (size_t)k0 * N);
        float4 b1 = *reinterpret_cast<const float4*>(Bp1 + (size_t)k0 * N);
        __syncthreads();
        As[ac + 0][ar] = a0.x; As[ac + 1][ar] = a0.y;
        As[ac + 2][ar] = a0.z; As[ac + 3][ar] = a0.w;
        As[ac + 0][ar + 64] = a1.x; As[ac + 1][ar + 64] = a1.y;
        As[ac + 2][ar + 64] = a1.z; As[ac + 3][ar + 64] = a1.w;
        *reinterpret_cast<float4*>(&Bs[br][bc])     = b0;
        *reinterpret_cast<float4*>(&Bs[br + 8][bc]) = b1;
        __syncthreads();
#pragma unroll
        for (int k = 0; k < 16; ++k) {
            float4 xa0 = *reinterpret_cast<const float4*>(&As[k][ty << 2]);
            float4 xa1 = *reinterpret_cast<const float4*>(&As[k][(ty << 2) + 64]);
            float4 xb0 = *reinterpret_cast<const float4*>(&Bs[k][tx << 2]);
            float4 xb1 = *reinterpret_cast<const float4*>(&Bs[k][(tx << 2) + 64]);
            float av[8] = {xa0.x, xa0.y, xa0.z, xa0.w, xa1.x, xa1.y, xa1.z, xa1.w};
            float bv[8] = {xb0.x, xb0.y, xb0.z, xb0.w, xb1.x, xb1.y, xb1.z, xb1.w};
#pragma unroll
            for (int i = 0; i < 8; ++i)
#pragma unroll
                for (int j = 0; j < 8; ++j)
                    acc[i][j] = fmaf(av[i], bv[j], acc[i][j]);
        }
    }
#pragma unroll
    for (int i = 0; i < 8; ++i) {
        int r = row0 + (ty << 2) + (i & 3) + ((i & 4) << 4);
        float* Crow = C + (size_t)r * N;
#pragma unroll
        for (int jh = 0; jh < 2; ++jh) {
            int cc = col0 + (tx << 2) + (jh << 6);
            float4 v;
            v.x = acc[i][jh * 4 + 0] + bias[cc + 0];
            v.y = acc[i][jh * 4 + 1] + bias[cc + 1];
            v.z = acc[i][jh * 4 + 2] + bias[cc + 2];
            v.w = acc[i][jh * 4 + 3] + bias[cc + 3];
            *reinterpret_cast<float4*>(Crow + cc) = v;
        }
    }
}

// ---------------------------------------------------------------------------
// Sim + argmax: 2-split / 3-product MFMA (hh + hm + mh; dropped-mm ~2e-6)
// with per-(row, split, column-half) TOP-2 tracking; exact fp32 rescore of
// all 32 candidates/row recovers the true argmax.
// ---------------------------------------------------------------------------
#define EPL 8192   // u16 per 128x64 emb plane tile
__global__ __launch_bounds__(256, 2) void argmax_mfma(
        const u16* __restrict__ Zh, const u16* __restrict__ Zm,
        const u16* __restrict__ Eh, const u16* __restrict__ Em,
        unsigned* __restrict__ pcand) {
    __shared__ u16 Bsh[2 * EPL];          // 32 KiB
    const int rb = blockIdx.x, split = blockIdx.y;
    const int row0 = rb * 128, cbase = split * 1024;
    const int t = threadIdx.x;
    const int w = t >> 6, lane = t & 63, lm = lane & 15, q = lane >> 4;
    const int wr = (w >> 1) * 64, wc = (w & 1) * 64;

    const int sr8 = lane >> 3;
    const int sc8 = lane & 7;

    // Resident A fragments (hi, mid): [plane][mtile][kstep]
    bf16x8 a[2][4][2];
#pragma unroll
    for (int i = 0; i < 4; ++i) {
        int row = row0 + wr + i * 16 + lm;
#pragma unroll
        for (int ks = 0; ks < 2; ++ks) {
            size_t off = (size_t)row * 64 + ks * 32 + q * 8;
            a[0][i][ks] = *reinterpret_cast<const bf16x8*>(Zh + off);
            a[1][i][ks] = *reinterpret_cast<const bf16x8*>(Zm + off);
        }
    }

    float v1[4][4], v2[4][4];
    int   i1[4][4], i2[4][4];
#pragma unroll
    for (int i = 0; i < 4; ++i)
#pragma unroll
        for (int r = 0; r < 4; ++r) {
            v1[i][r] = -3.0e38f; v2[i][r] = -3.0e38f;
            i1[i][r] = 0;        i2[i][r] = 0;
        }

    for (int c = 0; c < 8; ++c) {
        const int code0 = cbase + c * 128;
        __syncthreads();
#pragma unroll
        for (int p = 0; p < 2; ++p) {
            const u16* Ep = (p == 0) ? Eh : Em;
#pragma unroll
            for (int rr = 0; rr < 4; ++rr) {
                int g = rr * 4 + w;            // 8-row group 0..15
                int r = g * 8 + sr8;           // local code row 0..127
                int cg = sc8 ^ (r & 7);        // swizzled source chunk
                gll16(Ep + (size_t)(code0 + r) * 64 + cg * 8,
                      &Bsh[p * EPL + g * 512 + lane * 8]);
            }
        }
        __syncthreads();
#pragma unroll
        for (int j = 0; j < 4; ++j) {
            int rl = wc + j * 16 + lm;
            int nb = rl * 64;
            int s0 = (q ^ (rl & 7)) * 8;         // kstep 0 chunk
            int s1 = ((4 + q) ^ (rl & 7)) * 8;   // kstep 1 chunk
            bf16x8 eh0 = *reinterpret_cast<const bf16x8*>(&Bsh[0 * EPL + nb + s0]);
            bf16x8 eh1 = *reinterpret_cast<const bf16x8*>(&Bsh[0 * EPL + nb + s1]);
            bf16x8 em0 = *reinterpret_cast<const bf16x8*>(&Bsh[1 * EPL + nb + s0]);
            bf16x8 em1 = *reinterpret_cast<const bf16x8*>(&Bsh[1 * EPL + nb + s1]);
            int code = code0 + rl;
#pragma unroll
            for (int i = 0; i < 4; ++i) {
                f32x4 s = (f32x4){0.f, 0.f, 0.f, 0.f};
                s = __builtin_amdgcn_mfma_f32_16x16x32_bf16(a[0][i][0], em0, s, 0, 0, 0);
                s = __builtin_amdgcn_mfma_f32_16x16x32_bf16(a[1][i][0], eh0, s, 0, 0, 0);
                s = __builtin_amdgcn_mfma_f32_16x16x32_bf16(a[0][i][0], eh0, s, 0, 0, 0);
                s = __builtin_amdgcn_mfma_f32_16x16x32_bf16(a[0][i][1], em1, s, 0, 0, 0);
                s = __builtin_amdgcn_mfma_f32_16x16x32_bf16(a[1][i][1], eh1, s, 0, 0, 0);
                s = __builtin_amdgcn_mfma_f32_16x16x32_bf16(a[0][i][1], eh1, s, 0, 0, 0);
                // top-2 update (codes ascending; strict > keeps lowest idx)
#pragma unroll
                for (int r = 0; r < 4; ++r) {
                    float sv = s[r];
                    bool g1 = sv > v1[i][r];
                    bool g2 = sv > v2[i][r];
                    v2[i][r] = fminf(fmaxf(sv, v2[i][r]), v1[i][r]);   // med3
                    i2[i][r] = g1 ? i1[i][r] : (g2 ? code : i2[i][r]);
                    v1[i][r] = fmaxf(sv, v1[i][r]);
                    i1[i][r] = g1 ? code : i1[i][r];
                }
            }
        }
    }
    // merge top-2 across the 16 lanes sharing each row (lm bits 0..3)
#pragma unroll
    for (int i = 0; i < 4; ++i)
#pragma unroll
        for (int r = 0; r < 4; ++r) {
            float a1 = v1[i][r], a2 = v2[i][r];
            int   b1 = i1[i][r], b2 = i2[i][r];
#pragma unroll
            for (int msk = 1; msk <= 8; msk <<= 1) {
                float o1 = __shfl_xor(a1, msk, 64); int p1 = __shfl_xor(b1, msk, 64);
                float o2 = __shfl_xor(a2, msk, 64); int p2 = __shfl_xor(b2, msk, 64);
                bool ob = (o1 > a1) || (o1 == a1 && p1 < b1);
                float t1v = ob ? o1 : a1; int t1i = ob ? p1 : b1;
                float l1v = ob ? a1 : o1; int l1i = ob ? b1 : p1;
                bool o2b = (o2 > a2) || (o2 == a2 && p2 < b2);
                float w2v = o2b ? o2 : a2; int w2i = o2b ? p2 : b2;
                bool lb = (l1v > w2v) || (l1v == w2v && l1i < w2i);
                a1 = t1v; b1 = t1i;
                a2 = lb ? l1v : w2v; b2 = lb ? l1i : w2i;
            }
            if (lm == 0) {
                int row = row0 + wr + i * 16 + q * 4 + r;
                pcand[((size_t)row * 8 + split) * 2 + (w & 1)] =
                    (unsigned)b1 | ((unsigned)b2 << 16);
            }
        }
}

// ---------------------------------------------------------------------------
// Exact fp32 rescore of 32 candidates/row -> final idx + loss contribution.
// One wave per row; 2 lanes per candidate (32 elems each). emb rows and Zn
// are unit-norm, so loss_row = 2 - 2*best_sim (error ~1e-7 << threshold).
// ---------------------------------------------------------------------------
__global__ __launch_bounds__(256) void rescore_k(const float* __restrict__ Zn,
                                                 const float* __restrict__ emb,
                                                 const unsigned* __restrict__ pcand,
                                                 int* __restrict__ idx,
                                                 float* __restrict__ loss) {
    const int t = threadIdx.x;
    const int w = t >> 6, lane = t & 63;
    const int row = blockIdx.x * 4 + w;
    const int c = lane >> 1, h = lane & 1;
    unsigned word = pcand[(size_t)row * 16 + (c >> 1)];
    int id = (c & 1) ? (int)(word >> 16) : (int)(word & 0xffffu);
    const float4* zp = reinterpret_cast<const float4*>(Zn + (size_t)row * 64 + h * 32);
    const float4* ep = reinterpret_cast<const float4*>(emb + (size_t)id * 64 + h * 32);
    float acc = 0.0f;
#pragma unroll
    for (int k = 0; k < 8; ++k) {
        float4 z = zp[k], e = ep[k];
        acc += z.x * e.x + z.y * e.y + z.z * e.z + z.w * e.w;
    }
    acc += __shfl_xor(acc, 1, 64);   // both lanes of a pair: full dot
#pragma unroll
    for (int msk = 2; msk <= 32; msk <<= 1) {
        float ov = __shfl_xor(acc, msk, 64);
        int  oid = __shfl_xor(id, msk, 64);
        if (ov > acc || (ov == acc && oid < id)) { acc = ov; id = oid; }
    }
    if (lane == 0) {
        idx[row] = id;
        atomicAdd(loss, (2.0f - 2.0f * acc) * (1.0f / 1048576.0f));
    }
}

// out[n,:] = P[idx[n],:] — MUST run as its own kernel BEFORE onehot_k:
// P lives inside the codex scratch region that onehot_k overwrites.
__global__ __launch_bounds__(192) void gather_k(const int* __restrict__ idx,
                                                const float* __restrict__ P,
                                                float* __restrict__ out) {
    const int r = blockIdx.x;
    const int t = threadIdx.x;
    const int k = idx[r];
    float4 v = *reinterpret_cast<const float4*>(&P[(size_t)k * 768 + t * 4]);
    *reinterpret_cast<float4*>(&out[(size_t)r * 768 + t * 4]) = v;
}

// codex_probs: write the full one-hot matrix in one streaming pass.
__global__ __launch_bounds__(256) void onehot_k(const int* __restrict__ idx,
                                                float* __restrict__ codex) {
    const int row = blockIdx.x;
    const int k = idx[row];
    float* base = codex + (size_t)row * 8192;
#pragma unroll
    for (int it = 0; it < 8; ++it) {
        int col = it * 1024 + threadIdx.x * 4;
        float4 v = {0.f, 0.f, 0.f, 0.f};
        unsigned d = (unsigned)(k - col);
        if (d < 4u) (&v.x)[d] = 1.0f;
        *reinterpret_cast<float4*>(base + col) = v;
    }
}

// ---------------------------------------------------------------------------
extern "C" void kernel_launch(void* const* d_in, const int* in_sizes, int n_in,
                              void* d_out, int out_size, void* d_ws, size_t ws_size,
                              hipStream_t stream) {
    const float* Z     = (const float*)d_in[0];
    const float* W1    = (const float*)d_in[1];
    const float* b1    = (const float*)d_in[2];
    const float* W2    = (const float*)d_in[3];
    const float* b2    = (const float*)d_in[4];
    const float* emb   = (const float*)d_in[5];
    const float* gamma = (const float*)d_in[6];
    const float* beta  = (const float*)d_in[7];
    const float* Wp    = (const float*)d_in[8];
    const float* bp    = (const float*)d_in[9];

    float* outF  = (float*)d_out;
    float* H     = outF + H_OFF;
    float* P     = outF + P_OFF;
    float* Zn    = outF + ZN_OFF;
    float* Q     = outF + Q_OFF;
    u16*   ZH    = (u16*)(outF + ZH_OFF);
    u16*   ZM    = (u16*)(outF + ZM_OFF);
    u16*   ZL    = (u16*)(outF + ZL_OFF);
    u16*   W1H   = (u16*)(outF + W1H_OFF);
    u16*   W1M   = (u16*)(outF + W1M_OFF);
    u16*   W1L   = (u16*)(outF + W1L_OFF);
    u16*   NH    = (u16*)(outF + NH_OFF);
    u16*   NM    = (u16*)(outF + NM_OFF);
    u16*   EH    = (u16*)(outF + EH_OFF);
    u16*   EM    = (u16*)(outF + EM_OFF);
    float* lossp = outF + OUT_LOSS;
    float* codex = outF + OUT_CODEX;

    unsigned* pcand = (unsigned*)d_ws;                 // 16384*16 u32 = 1 MB
    int*      idxp  = (int*)((char*)d_ws + 1048576);   // 16384 ints

    // 1) fused prep: Z/W1 splits, emb hi/mid planes, Q, loss=0
    prep_k<<<8768, 256, 0, stream>>>(Z, W1, emb, gamma, beta,
                                     ZH, ZM, ZL, W1H, W1M, W1L, EH, EM, Q, lossp);
    // 2) H = tanh(Z @ W1 + b1)   (MFMA bf16x3, 6 products, 3 blocks/CU)
    gemm1_mfma<<<768, 256, 0, stream>>>(ZH, ZM, ZL, W1H, W1M, W1L, b1, H);
    // 3) Zn = l2norm(H @ W2 + b2) + hi/mid planes
    gemm2_l2<<<512, 256, 0, stream>>>(H, W2, b2, Zn, NH, NM);
    // 4) P = Q @ Wp + bp
    gemm128<<<dim3(6, 64), 256, 0, stream>>>(Q, Wp, bp, P, KCODES, DMODEL, DCODE);
    // 5) sim top-2 candidates per (row, split, half)  (MFMA bf16x2, 3 products)
    argmax_mfma<<<dim3(128, 8), 256, 0, stream>>>(NH, NM, EH, EM, pcand);
    // 6) exact fp32 rescore of 32 candidates -> idx, loss
    rescore_k<<<4096, 256, 0, stream>>>(Zn, emb, pcand, idxp, lossp);
    // 7) out[n] = P[idx[n]]  (reads P: must complete before onehot_k clobbers it)
    gather_k<<<16384, 192, 0, stream>>>(idxp, P, outF);
    // 8) codex one-hot (also wipes the scratch region deterministically)
    onehot_k<<<16384, 256, 0, stream>>>(idxp, codex);
}

// Round 8
// 1171.365 us; speedup vs baseline: 1.0007x; 1.0007x over previous
//
#include <hip/hip_runtime.h>
#include <cstddef>
#include <cstdint>

typedef unsigned short u16;
typedef short bf16x8 __attribute__((ext_vector_type(8)));
typedef float f32x4 __attribute__((ext_vector_type(4)));

// Problem constants (B=16, S=1024, D=768, DC=64, K=8192)
#define NROW   16384
#define DMODEL 768
#define DCODE  64
#define KCODES 8192

// d_out layout (float element offsets): [out 16384*768][loss 1][codex 16384*8192]
#define OUT_LOSS  12582912
#define OUT_CODEX 12582913
// 16B-aligned scratch carved out of the codex region. NOTE: everything here
// (incl. P) is clobbered by onehot_k — all readers MUST complete first
// (stream order). R6 fused gather into onehot and raced on P. Never fuse a
// reader of this region with the one-hot writer.
#define S0        12582916
#define H_OFF     (S0)                        // 12582912 f
#define P_OFF     (H_OFF + 12582912)          // 6291456 f
#define ZN_OFF    (P_OFF + 6291456)           // 1048576 f
#define Q_OFF     (ZN_OFF + 1048576)          // 524288 f
#define ZH_OFF    (Q_OFF + 524288)            // u16 planes of Z: each 6291456 f
#define ZM_OFF    (ZH_OFF + 6291456)
#define ZL_OFF    (ZM_OFF + 6291456)
#define W1H_OFF   (ZL_OFF + 6291456)          // W1^T planes: each 294912 f
#define W1M_OFF   (W1H_OFF + 294912)
#define W1L_OFF   (W1M_OFF + 294912)
#define NH_OFF    (W1L_OFF + 294912)          // Zn planes (hi, mid): each 524288 f
#define NM_OFF    (NH_OFF + 524288)
#define EH_OFF    (NM_OFF + 524288)           // emb planes (hi, mid): each 262144 f
#define EM_OFF    (EH_OFF + 262144)

__device__ __forceinline__ u16 f2bf(float x) {
    unsigned u = __float_as_uint(x);
    u += 0x7fffu + ((u >> 16) & 1u);          // RTNE
    return (u16)(u >> 16);
}
__device__ __forceinline__ float bf2f(u16 h) {
    return __uint_as_float(((unsigned)h) << 16);
}

// async global->LDS, 16 B per lane. LDS dest is wave-uniform base + lane*16
// (m104/m108): callers must pass lds = base + lane*16 exactly.
typedef __attribute__((address_space(1))) const unsigned int gas_u32;
typedef __attribute__((address_space(3))) unsigned int las_u32;
__device__ __forceinline__ void gll16(const u16* g, u16* l) {
    __builtin_amdgcn_global_load_lds((gas_u32*)g, (las_u32*)l, 16, 0, 0);
}

// ---------------------------------------------------------------------------
// Fused prep: blocks [0,6144) split Z into 3 bf16 planes; [6144,6720) split+
// transpose W1 into 3 planes; [6720,8768) emb -> hi/mid planes + Q=LN(emb).
// Block 6144 thread 0 also zeroes the loss slot (replaces a memset launch).
// ---------------------------------------------------------------------------
__global__ __launch_bounds__(256) void prep_k(const float* __restrict__ Z,
                                              const float* __restrict__ W1,
                                              const float* __restrict__ emb,
                                              const float* __restrict__ gamma,
                                              const float* __restrict__ beta,
                                              u16* __restrict__ Ph,
                                              u16* __restrict__ Pm,
                                              u16* __restrict__ Pl,
                                              u16* __restrict__ Th,
                                              u16* __restrict__ Tm,
                                              u16* __restrict__ Tl,
                                              u16* __restrict__ Eh,
                                              u16* __restrict__ Em,
                                              float* __restrict__ Q,
                                              float* __restrict__ lossp) {
    __shared__ float tile[32][33];
    const int b = blockIdx.x, t = threadIdx.x;
    if (b < 6144) {
        // ---- split Z, 8 elems/thread ----
        const size_t g = (size_t)b * 256 + t;
        const float4* zp = reinterpret_cast<const float4*>(Z) + g * 2;
        float4 a = zp[0], bb = zp[1];
        float xs[8] = {a.x, a.y, a.z, a.w, bb.x, bb.y, bb.z, bb.w};
        union { u16 u[8]; uint4 v; } ph, pm, pl;
#pragma unroll
        for (int k = 0; k < 8; ++k) {
            float x = xs[k];
            u16 h = f2bf(x); float r = x - bf2f(h);
            u16 m = f2bf(r); float r2 = r - bf2f(m);
            pl.u[k] = f2bf(r2); ph.u[k] = h; pm.u[k] = m;
        }
        *reinterpret_cast<uint4*>(Ph + g * 8) = ph.v;
        *reinterpret_cast<uint4*>(Pm + g * 8) = pm.v;
        *reinterpret_cast<uint4*>(Pl + g * 8) = pl.v;
    } else if (b < 6720) {
        // ---- split + transpose W1 (32x32 tile) ----
        if (b == 6144 && t == 0) *lossp = 0.0f;
        const int bb = b - 6144;
        const int n0 = (bb % 24) * 32, k0 = (bb / 24) * 32;
        const int tc = t & 31, tr = t >> 5;
#pragma unroll
        for (int rr = 0; rr < 4; ++rr) {
            int r = tr * 4 + rr;
            tile[r][tc] = W1[(size_t)(k0 + r) * 768 + n0 + tc];
        }
        __syncthreads();
#pragma unroll
        for (int rr = 0; rr < 4; ++rr) {
            int n = n0 + tr * 4 + rr;
            int k = k0 + tc;
            float x = tile[tc][tr * 4 + rr];
            u16 h = f2bf(x); float r = x - bf2f(h);
            u16 m = f2bf(r); u16 l = f2bf(r - bf2f(m));
            Th[(size_t)n * 768 + k] = h;
            Tm[(size_t)n * 768 + k] = m;
            Tl[(size_t)n * 768 + k] = l;
        }
    } else {
        // ---- emb hi/mid planes + Q = LN(emb)*gamma+beta, one wave/row ----
        const int lane = t & 63;
        const int n = (b - 6720) * 4 + (t >> 6);
        float x = emb[(size_t)n * 64 + lane];
        u16 h = f2bf(x); float r = x - bf2f(h);
        Eh[(size_t)n * 64 + lane] = h;
        Em[(size_t)n * 64 + lane] = f2bf(r);
        float mu = x;
#pragma unroll
        for (int off = 32; off > 0; off >>= 1) mu += __shfl_xor(mu, off, 64);
        mu *= (1.0f / 64.0f);
        float d = x - mu;
        float var = d * d;
#pragma unroll
        for (int off = 32; off > 0; off >>= 1) var += __shfl_xor(var, off, 64);
        var *= (1.0f / 64.0f);
        Q[(size_t)n * 64 + lane] = d * rsqrtf(var + 1e-5f) * gamma[lane] + beta[lane];
    }
}

// ---------------------------------------------------------------------------
// GEMM1 via 6-product bf16x3 MFMA: H = tanh(Z @ W1 + b1).
// M=16384, N=768, K=768. BM=128, BN=128, BK=32. LDS 48 KiB.
// global_load_lds(16B) staging, XOR chunk swizzle on the global side.
// v4: REVERT to __launch_bounds__(256,2) — R7's (256,3) caps VGPR at ~170
// with ~165-175 live -> suspected scratch spills in the K-loop (R5->R7 net
// zero despite halved argmax). (256,2) lets the allocator breathe; LDS
// (3x48 KiB <= 160 KiB) still admits 3 blocks/CU if VGPRs come in <=~170.
// ---------------------------------------------------------------------------
#define APL 4096   // u16 per 128x32 plane tile
__global__ __launch_bounds__(256, 2) void gemm1_mfma(
        const u16* __restrict__ Ah0, const u16* __restrict__ Am0, const u16* __restrict__ Al0,
        const u16* __restrict__ Bh0, const u16* __restrict__ Bm0, const u16* __restrict__ Bl0,
        const float* __restrict__ bias, float* __restrict__ H) {
    __shared__ u16 lds[6 * APL];          // A planes 0..2, B planes 3..5

    const int b = blockIdx.x;
    const int xcd = b & 7, ii = b >> 3;
    const int row0 = (xcd * 16 + (ii & 15)) * 128;
    const int col0 = (ii >> 4) * 128;

    const int t = threadIdx.x;
    const int w = t >> 6, lane = t & 63, lm = lane & 15, q = lane >> 4;
    const int wr = (w >> 1) * 64, wc = (w & 1) * 64;

    const u16* Ap[3] = {Ah0, Am0, Al0};
    const u16* Bp[3] = {Bh0, Bm0, Bl0};

    const int sr  = lane >> 2;        // row within 16-row group
    const int scc = lane & 3;         // LDS chunk slot

    f32x4 acc[4][4];
#pragma unroll
    for (int i = 0; i < 4; ++i)
#pragma unroll
        for (int j = 0; j < 4; ++j) acc[i][j] = (f32x4){0.f, 0.f, 0.f, 0.f};

    for (int k0 = 0; k0 < 768; k0 += 32) {
        __syncthreads();
#pragma unroll
        for (int p = 0; p < 3; ++p) {
#pragma unroll
            for (int rr = 0; rr < 2; ++rr) {
                int g = rr * 4 + w;               // 16-row group 0..7
                int r = g * 16 + sr;              // local row 0..127
                int cg = scc ^ ((r >> 1) & 3);    // swizzled source chunk
                gll16(Ap[p] + (size_t)(row0 + r) * 768 + k0 + cg * 8,
                      &lds[p * APL + g * 512 + lane * 8]);
                gll16(Bp[p] + (size_t)(col0 + r) * 768 + k0 + cg * 8,
                      &lds[(3 + p) * APL + g * 512 + lane * 8]);
            }
        }
        __syncthreads();

        bf16x8 fah[4], fam[4], fal[4];
#pragma unroll
        for (int i = 0; i < 4; ++i) {
            int r = wr + i * 16 + lm;
            int off = r * 32 + ((q ^ ((r >> 1) & 3)) * 8);
            fah[i] = *reinterpret_cast<const bf16x8*>(&lds[0 * APL + off]);
            fam[i] = *reinterpret_cast<const bf16x8*>(&lds[1 * APL + off]);
            fal[i] = *reinterpret_cast<const bf16x8*>(&lds[2 * APL + off]);
        }
#pragma unroll
        for (int j = 0; j < 4; ++j) {
            int rb = wc + j * 16 + lm;
            int offb = rb * 32 + ((q ^ ((rb >> 1) & 3)) * 8);
            bf16x8 fbh = *reinterpret_cast<const bf16x8*>(&lds[3 * APL + offb]);
            bf16x8 fbm = *reinterpret_cast<const bf16x8*>(&lds[4 * APL + offb]);
            bf16x8 fbl = *reinterpret_cast<const bf16x8*>(&lds[5 * APL + offb]);
#pragma unroll
            for (int i = 0; i < 4; ++i) {
                f32x4 c = acc[i][j];
                c = __builtin_amdgcn_mfma_f32_16x16x32_bf16(fah[i], fbl, c, 0, 0, 0);
                c = __builtin_amdgcn_mfma_f32_16x16x32_bf16(fal[i], fbh, c, 0, 0, 0);
                c = __builtin_amdgcn_mfma_f32_16x16x32_bf16(fam[i], fbm, c, 0, 0, 0);
                c = __builtin_amdgcn_mfma_f32_16x16x32_bf16(fah[i], fbm, c, 0, 0, 0);
                c = __builtin_amdgcn_mfma_f32_16x16x32_bf16(fam[i], fbh, c, 0, 0, 0);
                c = __builtin_amdgcn_mfma_f32_16x16x32_bf16(fah[i], fbh, c, 0, 0, 0);
                acc[i][j] = c;
            }
        }
    }
    // epilogue: +bias, tanh, store
#pragma unroll
    for (int i = 0; i < 4; ++i)
#pragma unroll
        for (int j = 0; j < 4; ++j) {
            int col = col0 + wc + j * 16 + lm;
            float bv = bias[col];
#pragma unroll
            for (int r = 0; r < 4; ++r) {
                int row = row0 + wr + i * 16 + q * 4 + r;
                H[(size_t)row * 768 + col] = tanhf(acc[i][j][r] + bv);
            }
        }
}

// ---------------------------------------------------------------------------
// GEMM2 fused with l2norm: Zn = l2norm(H @ W2 + b2) + hi/mid bf16 planes.
// M=16384, N=64(full), K=768. fp32 vector. BM=32 -> 512 blocks (2/CU).
// ---------------------------------------------------------------------------
__global__ __launch_bounds__(256) void gemm2_l2(const float* __restrict__ A,
                                                const float* __restrict__ B,
                                                const float* __restrict__ bias,
                                                float* __restrict__ Zn,
                                                u16* __restrict__ Nh,
                                                u16* __restrict__ Nm) {
    __shared__ float As[16][32];
    __shared__ float Bs[16][64];
    const int t    = threadIdx.x;
    const int row0 = blockIdx.x * 32;
    const int tx = t & 15, ty = t >> 4;
    const int ar = t >> 2, ac = (t & 3) << 2;   // t<128 stages A
    const int br = t >> 4, bc = (t & 15) << 2;

    const float* Ap = A + (size_t)(row0 + ar) * 768 + ac;
    const float* Bp = B + (size_t)br * 64 + bc;

    float acc[2][4];
#pragma unroll
    for (int i = 0; i < 2; ++i)
#pragma unroll
        for (int j = 0; j < 4; ++j) acc[i][j] = 0.0f;

    for (int k0 = 0; k0 < 768; k0 += 16) {
        float4 a0;
        if (t < 128) a0 = *reinterpret_cast<const float4*>(Ap + k0);
        float4 b0 = *reinterpret_cast<const float4*>(Bp + (size_t)k0 * 64);
        __syncthreads();
        if (t < 128) {
            As[ac + 0][ar] = a0.x; As[ac + 1][ar] = a0.y;
            As[ac + 2][ar] = a0.z; As[ac + 3][ar] = a0.w;
        }
        *reinterpret_cast<float4*>(&Bs[br][bc]) = b0;
        __syncthreads();
#pragma unroll
        for (int k = 0; k < 16; ++k) {
            float av0 = As[k][ty * 2 + 0];
            float av1 = As[k][ty * 2 + 1];
            float4 xb = *reinterpret_cast<const float4*>(&Bs[k][tx << 2]);
            float bv[4] = {xb.x, xb.y, xb.z, xb.w};
#pragma unroll
            for (int j = 0; j < 4; ++j) {
                acc[0][j] = fmaf(av0, bv[j], acc[0][j]);
                acc[1][j] = fmaf(av1, bv[j], acc[1][j]);
            }
        }
    }
    const int c = tx << 2;
    const float4 bv4 = *reinterpret_cast<const float4*>(bias + c);
#pragma unroll
    for (int i = 0; i < 2; ++i) {
        float v0 = acc[i][0] + bv4.x;
        float v1 = acc[i][1] + bv4.y;
        float v2 = acc[i][2] + bv4.z;
        float v3 = acc[i][3] + bv4.w;
        float ss = v0 * v0 + v1 * v1 + v2 * v2 + v3 * v3;
#pragma unroll
        for (int msk = 1; msk <= 8; msk <<= 1) ss += __shfl_xor(ss, msk, 64);
        float sc = 1.0f / fmaxf(sqrtf(ss), 1e-12f);
        v0 *= sc; v1 *= sc; v2 *= sc; v3 *= sc;
        int r = row0 + ty * 2 + i;
        float4 z = {v0, v1, v2, v3};
        *reinterpret_cast<float4*>(Zn + (size_t)r * 64 + c) = z;
        float vs[4] = {v0, v1, v2, v3};
        u16 hu[4], mu_[4];
#pragma unroll
        for (int j = 0; j < 4; ++j) {
            u16 h = f2bf(vs[j]);
            hu[j] = h; mu_[j] = f2bf(vs[j] - bf2f(h));
        }
        *reinterpret_cast<ushort4*>(Nh + (size_t)r * 64 + c) =
            make_ushort4(hu[0], hu[1], hu[2], hu[3]);
        *reinterpret_cast<ushort4*>(Nm + (size_t)r * 64 + c) =
            make_ushort4(mu_[0], mu_[1], mu_[2], mu_[3]);
    }
}

// ---------------------------------------------------------------------------
// Generic 128x128x16 fp32 tiled GEMM (used for P = Q @ Wp + bp, K=64).
// ---------------------------------------------------------------------------
__global__ __launch_bounds__(256) void gemm128(const float* __restrict__ A,
                                               const float* __restrict__ B,
                                               const float* __restrict__ bias,
                                               float* __restrict__ C,
                                               int M, int N, int K) {
    __shared__ float As[16][128];
    __shared__ float Bs[16][128];
    const int t    = threadIdx.x;
    const int row0 = blockIdx.y * 128;
    const int col0 = blockIdx.x * 128;
    const int tx = t & 15, ty = t >> 4;
    const int ar = t >> 2, ac = (t & 3) << 2;
    const int br = t >> 5, bc = (t & 31) << 2;

    const float* Ap0 = A + (size_t)(row0 + ar) * K + ac;
    const float* Ap1 = Ap0 + (size_t)64 * K;
    const float* Bp0 = B + (size_t)br * N + col0 + bc;
    const float* Bp1 = Bp0 + (size_t)8 * N;

    float acc[8][8];
#pragma unroll
    for (int i = 0; i < 8; ++i)
#pragma unroll
        for (int j = 0; j < 8; ++j) acc[i][j] = 0.0f;

    for (int k0 = 0; k0 < K; k0 += 16) {
        float4 a0 = *reinterpret_cast<const float4*>(Ap0 + k0);
        float4 a1 = *reinterpret_cast<const float4*>(Ap1 + k0);
        float4 b0 = *reinterpret_cast<const float4*>(Bp0 + (size_t)k0 * N);
        float4 b1 = *reinterpret_cast<const float4*>(Bp1 + (size_t)k0 * N);
        __syncthreads();
        As[ac + 0][ar] = a0.x; As[ac + 1][ar] = a0.y;
        As[ac + 2][ar] = a0.z; As[ac + 3][ar] = a0.w;
        As[ac + 0][ar + 64] = a1.x; As[ac + 1][ar + 64] = a1.y;
        As[ac + 2][ar + 64] = a1.z; As[ac + 3][ar + 64] = a1.w;
        *reinterpret_cast<float4*>(&Bs[br][bc])     = b0;
        *reinterpret_cast<float4*>(&Bs[br + 8][bc]) = b1;
        __syncthreads();
#pragma unroll
        for (int k = 0; k < 16; ++k) {
            float4 xa0 = *reinterpret_cast<const float4*>(&As[k][ty << 2]);
            float4 xa1 = *reinterpret_cast<const float4*>(&As[k][(ty << 2) + 64]);
            float4 xb0 = *reinterpret_cast<const float4*>(&Bs[k][tx << 2]);
            float4 xb1 = *reinterpret_cast<const float4*>(&Bs[k][(tx << 2) + 64]);
            float av[8] = {xa0.x, xa0.y, xa0.z, xa0.w, xa1.x, xa1.y, xa1.z, xa1.w};
            float bv[8] = {xb0.x, xb0.y, xb0.z, xb0.w, xb1.x, xb1.y, xb1.z, xb1.w};
#pragma unroll
            for (int i = 0; i < 8; ++i)
#pragma unroll
                for (int j = 0; j < 8; ++j)
                    acc[i][j] = fmaf(av[i], bv[j], acc[i][j]);
        }
    }
#pragma unroll
    for (int i = 0; i < 8; ++i) {
        int r = row0 + (ty << 2) + (i & 3) + ((i & 4) << 4);
        float* Crow = C + (size_t)r * N;
#pragma unroll
        for (int jh = 0; jh < 2; ++jh) {
            int cc = col0 + (tx << 2) + (jh << 6);
            float4 v;
            v.x = acc[i][jh * 4 + 0] + bias[cc + 0];
            v.y = acc[i][jh * 4 + 1] + bias[cc + 1];
            v.z = acc[i][jh * 4 + 2] + bias[cc + 2];
            v.w = acc[i][jh * 4 + 3] + bias[cc + 3];
            *reinterpret_cast<float4*>(Crow + cc) = v;
        }
    }
}

// ---------------------------------------------------------------------------
// Sim + argmax: 2-split / 3-product MFMA (hh + hm + mh; dropped-mm ~2e-6)
// with per-(row, split, column-half) TOP-2 tracking; exact fp32 rescore of
// all 32 candidates/row recovers the true argmax.
// ---------------------------------------------------------------------------
#define EPL 8192   // u16 per 128x64 emb plane tile
__global__ __launch_bounds__(256, 2) void argmax_mfma(
        const u16* __restrict__ Zh, const u16* __restrict__ Zm,
        const u16* __restrict__ Eh, const u16* __restrict__ Em,
        unsigned* __restrict__ pcand) {
    __shared__ u16 Bsh[2 * EPL];          // 32 KiB
    const int rb = blockIdx.x, split = blockIdx.y;
    const int row0 = rb * 128, cbase = split * 1024;
    const int t = threadIdx.x;
    const int w = t >> 6, lane = t & 63, lm = lane & 15, q = lane >> 4;
    const int wr = (w >> 1) * 64, wc = (w & 1) * 64;

    const int sr8 = lane >> 3;
    const int sc8 = lane & 7;

    // Resident A fragments (hi, mid): [plane][mtile][kstep]
    bf16x8 a[2][4][2];
#pragma unroll
    for (int i = 0; i < 4; ++i) {
        int row = row0 + wr + i * 16 + lm;
#pragma unroll
        for (int ks = 0; ks < 2; ++ks) {
            size_t off = (size_t)row * 64 + ks * 32 + q * 8;
            a[0][i][ks] = *reinterpret_cast<const bf16x8*>(Zh + off);
            a[1][i][ks] = *reinterpret_cast<const bf16x8*>(Zm + off);
        }
    }

    float v1[4][4], v2[4][4];
    int   i1[4][4], i2[4][4];
#pragma unroll
    for (int i = 0; i < 4; ++i)
#pragma unroll
        for (int r = 0; r < 4; ++r) {
            v1[i][r] = -3.0e38f; v2[i][r] = -3.0e38f;
            i1[i][r] = 0;        i2[i][r] = 0;
        }

    for (int c = 0; c < 8; ++c) {
        const int code0 = cbase + c * 128;
        __syncthreads();
#pragma unroll
        for (int p = 0; p < 2; ++p) {
            const u16* Ep = (p == 0) ? Eh : Em;
#pragma unroll
            for (int rr = 0; rr < 4; ++rr) {
                int g = rr * 4 + w;            // 8-row group 0..15
                int r = g * 8 + sr8;           // local code row 0..127
                int cg = sc8 ^ (r & 7);        // swizzled source chunk
                gll16(Ep + (size_t)(code0 + r) * 64 + cg * 8,
                      &Bsh[p * EPL + g * 512 + lane * 8]);
            }
        }
        __syncthreads();
#pragma unroll
        for (int j = 0; j < 4; ++j) {
            int rl = wc + j * 16 + lm;
            int nb = rl * 64;
            int s0 = (q ^ (rl & 7)) * 8;         // kstep 0 chunk
            int s1 = ((4 + q) ^ (rl & 7)) * 8;   // kstep 1 chunk
            bf16x8 eh0 = *reinterpret_cast<const bf16x8*>(&Bsh[0 * EPL + nb + s0]);
            bf16x8 eh1 = *reinterpret_cast<const bf16x8*>(&Bsh[0 * EPL + nb + s1]);
            bf16x8 em0 = *reinterpret_cast<const bf16x8*>(&Bsh[1 * EPL + nb + s0]);
            bf16x8 em1 = *reinterpret_cast<const bf16x8*>(&Bsh[1 * EPL + nb + s1]);
            int code = code0 + rl;
#pragma unroll
            for (int i = 0; i < 4; ++i) {
                f32x4 s = (f32x4){0.f, 0.f, 0.f, 0.f};
                s = __builtin_amdgcn_mfma_f32_16x16x32_bf16(a[0][i][0], em0, s, 0, 0, 0);
                s = __builtin_amdgcn_mfma_f32_16x16x32_bf16(a[1][i][0], eh0, s, 0, 0, 0);
                s = __builtin_amdgcn_mfma_f32_16x16x32_bf16(a[0][i][0], eh0, s, 0, 0, 0);
                s = __builtin_amdgcn_mfma_f32_16x16x32_bf16(a[0][i][1], em1, s, 0, 0, 0);
                s = __builtin_amdgcn_mfma_f32_16x16x32_bf16(a[1][i][1], eh1, s, 0, 0, 0);
                s = __builtin_amdgcn_mfma_f32_16x16x32_bf16(a[0][i][1], eh1, s, 0, 0, 0);
                // top-2 update (codes ascending; strict > keeps lowest idx)
#pragma unroll
                for (int r = 0; r < 4; ++r) {
                    float sv = s[r];
                    bool g1 = sv > v1[i][r];
                    bool g2 = sv > v2[i][r];
                    v2[i][r] = fminf(fmaxf(sv, v2[i][r]), v1[i][r]);   // med3
                    i2[i][r] = g1 ? i1[i][r] : (g2 ? code : i2[i][r]);
                    v1[i][r] = fmaxf(sv, v1[i][r]);
                    i1[i][r] = g1 ? code : i1[i][r];
                }
            }
        }
    }
    // merge top-2 across the 16 lanes sharing each row (lm bits 0..3)
#pragma unroll
    for (int i = 0; i < 4; ++i)
#pragma unroll
        for (int r = 0; r < 4; ++r) {
            float a1 = v1[i][r], a2 = v2[i][r];
            int   b1 = i1[i][r], b2 = i2[i][r];
#pragma unroll
            for (int msk = 1; msk <= 8; msk <<= 1) {
                float o1 = __shfl_xor(a1, msk, 64); int p1 = __shfl_xor(b1, msk, 64);
                float o2 = __shfl_xor(a2, msk, 64); int p2 = __shfl_xor(b2, msk, 64);
                bool ob = (o1 > a1) || (o1 == a1 && p1 < b1);
                float t1v = ob ? o1 : a1; int t1i = ob ? p1 : b1;
                float l1v = ob ? a1 : o1; int l1i = ob ? b1 : p1;
                bool o2b = (o2 > a2) || (o2 == a2 && p2 < b2);
                float w2v = o2b ? o2 : a2; int w2i = o2b ? p2 : b2;
                bool lb = (l1v > w2v) || (l1v == w2v && l1i < w2i);
                a1 = t1v; b1 = t1i;
                a2 = lb ? l1v : w2v; b2 = lb ? l1i : w2i;
            }
            if (lm == 0) {
                int row = row0 + wr + i * 16 + q * 4 + r;
                pcand[((size_t)row * 8 + split) * 2 + (w & 1)] =
                    (unsigned)b1 | ((unsigned)b2 << 16);
            }
        }
}

// ---------------------------------------------------------------------------
// Exact fp32 rescore of 32 candidates/row -> final idx + loss contribution.
// One wave per row; 2 lanes per candidate (32 elems each). emb rows and Zn
// are unit-norm, so loss_row = 2 - 2*best_sim (error ~1e-7 << threshold).
// ---------------------------------------------------------------------------
__global__ __launch_bounds__(256) void rescore_k(const float* __restrict__ Zn,
                                                 const float* __restrict__ emb,
                                                 const unsigned* __restrict__ pcand,
                                                 int* __restrict__ idx,
                                                 float* __restrict__ loss) {
    const int t = threadIdx.x;
    const int w = t >> 6, lane = t & 63;
    const int row = blockIdx.x * 4 + w;
    const int c = lane >> 1, h = lane & 1;
    unsigned word = pcand[(size_t)row * 16 + (c >> 1)];
    int id = (c & 1) ? (int)(word >> 16) : (int)(word & 0xffffu);
    const float4* zp = reinterpret_cast<const float4*>(Zn + (size_t)row * 64 + h * 32);
    const float4* ep = reinterpret_cast<const float4*>(emb + (size_t)id * 64 + h * 32);
    float acc = 0.0f;
#pragma unroll
    for (int k = 0; k < 8; ++k) {
        float4 z = zp[k], e = ep[k];
        acc += z.x * e.x + z.y * e.y + z.z * e.z + z.w * e.w;
    }
    acc += __shfl_xor(acc, 1, 64);   // both lanes of a pair: full dot
#pragma unroll
    for (int msk = 2; msk <= 32; msk <<= 1) {
        float ov = __shfl_xor(acc, msk, 64);
        int  oid = __shfl_xor(id, msk, 64);
        if (ov > acc || (ov == acc && oid < id)) { acc = ov; id = oid; }
    }
    if (lane == 0) {
        idx[row] = id;
        atomicAdd(loss, (2.0f - 2.0f * acc) * (1.0f / 1048576.0f));
    }
}

// out[n,:] = P[idx[n],:] — MUST run as its own kernel BEFORE onehot_k:
// P lives inside the codex scratch region that onehot_k overwrites.
__global__ __launch_bounds__(192) void gather_k(const int* __restrict__ idx,
                                                const float* __restrict__ P,
                                                float* __restrict__ out) {
    const int r = blockIdx.x;
    const int t = threadIdx.x;
    const int k = idx[r];
    float4 v = *reinterpret_cast<const float4*>(&P[(size_t)k * 768 + t * 4]);
    *reinterpret_cast<float4*>(&out[(size_t)r * 768 + t * 4]) = v;
}

// codex_probs: write the full one-hot matrix in one streaming pass.
__global__ __launch_bounds__(256) void onehot_k(const int* __restrict__ idx,
                                                float* __restrict__ codex) {
    const int row = blockIdx.x;
    const int k = idx[row];
    float* base = codex + (size_t)row * 8192;
#pragma unroll
    for (int it = 0; it < 8; ++it) {
        int col = it * 1024 + threadIdx.x * 4;
        float4 v = {0.f, 0.f, 0.f, 0.f};
        unsigned d = (unsigned)(k - col);
        if (d < 4u) (&v.x)[d] = 1.0f;
        *reinterpret_cast<float4*>(base + col) = v;
    }
}

// ---------------------------------------------------------------------------
extern "C" void kernel_launch(void* const* d_in, const int* in_sizes, int n_in,
                              void* d_out, int out_size, void* d_ws, size_t ws_size,
                              hipStream_t stream) {
    const float* Z     = (const float*)d_in[0];
    const float* W1    = (const float*)d_in[1];
    const float* b1    = (const float*)d_in[2];
    const float* W2    = (const float*)d_in[3];
    const float* b2    = (const float*)d_in[4];
    const float* emb   = (const float*)d_in[5];
    const float* gamma = (const float*)d_in[6];
    const float* beta  = (const float*)d_in[7];
    const float* Wp    = (const float*)d_in[8];
    const float* bp    = (const float*)d_in[9];

    float* outF  = (float*)d_out;
    float* H     = outF + H_OFF;
    float* P     = outF + P_OFF;
    float* Zn    = outF + ZN_OFF;
    float* Q     = outF + Q_OFF;
    u16*   ZH    = (u16*)(outF + ZH_OFF);
    u16*   ZM    = (u16*)(outF + ZM_OFF);
    u16*   ZL    = (u16*)(outF + ZL_OFF);
    u16*   W1H   = (u16*)(outF + W1H_OFF);
    u16*   W1M   = (u16*)(outF + W1M_OFF);
    u16*   W1L   = (u16*)(outF + W1L_OFF);
    u16*   NH    = (u16*)(outF + NH_OFF);
    u16*   NM    = (u16*)(outF + NM_OFF);
    u16*   EH    = (u16*)(outF + EH_OFF);
    u16*   EM    = (u16*)(outF + EM_OFF);
    float* lossp = outF + OUT_LOSS;
    float* codex = outF + OUT_CODEX;

    unsigned* pcand = (unsigned*)d_ws;                 // 16384*16 u32 = 1 MB
    int*      idxp  = (int*)((char*)d_ws + 1048576);   // 16384 ints

    // 1) fused prep: Z/W1 splits, emb hi/mid planes, Q, loss=0
    prep_k<<<8768, 256, 0, stream>>>(Z, W1, emb, gamma, beta,
                                     ZH, ZM, ZL, W1H, W1M, W1L, EH, EM, Q, lossp);
    // 2) H = tanh(Z @ W1 + b1)   (MFMA bf16x3, 6 products)
    gemm1_mfma<<<768, 256, 0, stream>>>(ZH, ZM, ZL, W1H, W1M, W1L, b1, H);
    // 3) Zn = l2norm(H @ W2 + b2) + hi/mid planes
    gemm2_l2<<<512, 256, 0, stream>>>(H, W2, b2, Zn, NH, NM);
    // 4) P = Q @ Wp + bp
    gemm128<<<dim3(6, 64), 256, 0, stream>>>(Q, Wp, bp, P, KCODES, DMODEL, DCODE);
    // 5) sim top-2 candidates per (row, split, half)  (MFMA bf16x2, 3 products)
    argmax_mfma<<<dim3(128, 8), 256, 0, stream>>>(NH, NM, EH, EM, pcand);
    // 6) exact fp32 rescore of 32 candidates -> idx, loss
    rescore_k<<<4096, 256, 0, stream>>>(Zn, emb, pcand, idxp, lossp);
    // 7) out[n] = P[idx[n]]  (reads P: must complete before onehot_k clobbers it)
    gather_k<<<16384, 192, 0, stream>>>(idxp, P, outF);
    // 8) codex one-hot (also wipes the scratch region deterministically)
    onehot_k<<<16384, 256, 0, stream>>>(idxp, codex);
}